// Round 12
// baseline (575.941 us; speedup 1.0000x reference)
//
#include <hip/hip_runtime.h>
#include <cfloat>

#define N_TOK   32768
#define DIM     64
#define K_CODES 8192
#define NCHK    32                 // 256-code chunks

#define IDX_OFF  (N_TOK * DIM)
#define LOSS_OFF (N_TOK * DIM + N_TOK)

// ws layout (float units): esq 8192 + ehi 262144 (1MB of bf16) + parts 128
#define WS_ESQ   0
#define WS_EHI   8192
#define WS_PART  270336

#define MRG   2e-5f     // strict slack: bound < every computed fl-d in chunk
#define DINIT 3e-5f     // init upper-bound slack (esq_max 1e-6 + 2 fl-roundings + margin)

typedef __attribute__((ext_vector_type(8)))  short bf16x8;
typedef __attribute__((ext_vector_type(16))) float f32x16;

__device__ inline ushort f2bf(float x) {          // round-to-nearest-even
    unsigned u = __float_as_uint(x);
    return (ushort)((u + 0x7FFFu + ((u >> 16) & 1u)) >> 16);
}
__device__ inline float bf2f(ushort h) { return __uint_as_float(((unsigned)h) << 16); }

// ---------------------------------------------------------------------------
// e_sq[k] = numpy-pairwise sum of squares (bitwise np order) — proven R1-R11.
// ---------------------------------------------------------------------------
__global__ __launch_bounds__(256) void esq_kernel(const float* __restrict__ emb,
                                                  float* __restrict__ esq) {
#pragma clang fp contract(off)
    const int tid = threadIdx.x;
    const int q = tid & 7;
    const int code = blockIdx.x * 32 + (tid >> 3);
    const float* row = emb + code * DIM;
    float x = row[q];
    float r = x * x;
#pragma unroll
    for (int m = 1; m < 8; ++m) {
        float y = row[q + 8 * m];
        float sq = y * y;
        r = r + sq;
    }
    r = r + __shfl_xor(r, 1, 64);
    r = r + __shfl_xor(r, 2, 64);
    r = r + __shfl_xor(r, 4, 64);
    if (q == 0) esq[code] = r;
}

// ---------------------------------------------------------------------------
// Pack embedding rows to bf16 (RN) once: ehi[k][d], code-major 128B rows.
// ---------------------------------------------------------------------------
__global__ __launch_bounds__(256) void pack_hi(const float* __restrict__ emb,
                                               ushort* __restrict__ ehi) {
#pragma clang fp contract(off)
    const int k = blockIdx.x * 256 + threadIdx.x;     // grid 32 -> 8192 codes
    const float4* ep = (const float4*)(emb + (size_t)k * DIM);
    ushort* op = ehi + (size_t)k * DIM;
#pragma unroll
    for (int i = 0; i < 8; ++i) {
        const float4 a = ep[2 * i], b = ep[2 * i + 1];
        const float zz[8] = {a.x, a.y, a.z, a.w, b.x, b.y, b.z, b.w};
        bf16x8 v;
#pragma unroll
        for (int e = 0; e < 8; ++e) v[e] = (short)f2bf(zz[e]);
        *(bf16x8*)(op + 8 * i) = v;
    }
}

// ---------------------------------------------------------------------------
// MFMA sweep (unchanged from R10/R11, passed): A=e bf16 global, B=z hi/lo regs.
// Mm[token][chunk] f32 upper-ish dot max (eps-covered) in d_out scratch.
// ---------------------------------------------------------------------------
__global__ __launch_bounds__(256, 2) void vq_mfma(const float* __restrict__ hid,
                                                  const ushort* __restrict__ ehi,
                                                  float* __restrict__ Mm) {
#pragma clang fp contract(off)
    __shared__ float tmw[4][64];

    const int tid = threadIdx.x;
    const int lane = tid & 63;
    const int w = tid >> 6;
    const int h = lane >> 5;
    const int t0 = blockIdx.x * 64;

    bf16x8 z_hi[2][4], z_lo[2][4];
#pragma unroll
    for (int ts = 0; ts < 2; ++ts)
#pragma unroll
    for (int q = 0; q < 4; ++q) {
        const float* zp = hid + (size_t)(t0 + 32 * ts + (lane & 31)) * DIM + 16 * q + 8 * h;
        const float4 u0 = *(const float4*)zp;
        const float4 u1 = *(const float4*)(zp + 4);
        const float zz[8] = {u0.x, u0.y, u0.z, u0.w, u1.x, u1.y, u1.z, u1.w};
        bf16x8 hv, lv;
#pragma unroll
        for (int i = 0; i < 8; ++i) {
            const ushort hb = f2bf(zz[i]);
            hv[i] = (short)hb;
            lv[i] = (short)f2bf(zz[i] - bf2f(hb));
        }
        z_hi[ts][q] = hv; z_lo[ts][q] = lv;
    }

    f32x16 zc;
#pragma unroll
    for (int i = 0; i < 16; ++i) zc[i] = 0.0f;

    const ushort* abase = ehi + (size_t)(32 * w + (lane & 31)) * DIM + 8 * h;

    bf16x8 a_cur[4], a_nxt[4];
#pragma unroll
    for (int q = 0; q < 4; ++q)
        a_cur[q] = *(const bf16x8*)(abase + 16 * q);

    float wm0 = -3.0e38f, wm1 = -3.0e38f;

    for (int sc = 0; sc < 64; ++sc) {
        const int scn = (sc + 1 < 64) ? (sc + 1) : 63;
#pragma unroll
        for (int q = 0; q < 4; ++q)
            a_nxt[q] = *(const bf16x8*)(abase + (size_t)scn * 128 * DIM + 16 * q);

        f32x16 d0, d1;
#pragma unroll
        for (int q = 0; q < 4; ++q) {
            if (q == 0) {
                d0 = __builtin_amdgcn_mfma_f32_32x32x16_bf16(a_cur[0], z_hi[0][0], zc, 0, 0, 0);
                d1 = __builtin_amdgcn_mfma_f32_32x32x16_bf16(a_cur[0], z_hi[1][0], zc, 0, 0, 0);
            } else {
                d0 = __builtin_amdgcn_mfma_f32_32x32x16_bf16(a_cur[q], z_hi[0][q], d0, 0, 0, 0);
                d1 = __builtin_amdgcn_mfma_f32_32x32x16_bf16(a_cur[q], z_hi[1][q], d1, 0, 0, 0);
            }
            d0 = __builtin_amdgcn_mfma_f32_32x32x16_bf16(a_cur[q], z_lo[0][q], d0, 0, 0, 0);
            d1 = __builtin_amdgcn_mfma_f32_32x32x16_bf16(a_cur[q], z_lo[1][q], d1, 0, 0, 0);
        }
#pragma unroll
        for (int i = 0; i < 16; ++i) {
            wm0 = fmaxf(wm0, d0[i]);
            wm1 = fmaxf(wm1, d1[i]);
        }

        if (sc & 1) {
            wm0 = fmaxf(wm0, __shfl_xor(wm0, 32, 64));
            wm1 = fmaxf(wm1, __shfl_xor(wm1, 32, 64));
            if (lane < 32) {
                tmw[w][lane] = wm0;
                tmw[w][32 + lane] = wm1;
            }
            __syncthreads();
            if (tid < 64) {
                const float m4 = fmaxf(fmaxf(tmw[0][tid], tmw[1][tid]),
                                       fmaxf(tmw[2][tid], tmw[3][tid]));
                Mm[(size_t)(t0 + tid) * NCHK + (sc >> 1)] = m4;
            }
            __syncthreads();
            wm0 = -3.0e38f; wm1 = -3.0e38f;
        }
#pragma unroll
        for (int q = 0; q < 4; ++q) a_cur[q] = a_nxt[q];
    }
}

// ---------------------------------------------------------------------------
// Exact selection v3: R11 structure + ev[64] PINNED in VGPRs via empty asm
// (defeats compiler rematerialization of the e-row gather inside the p-loop,
// which was R11's latency collapse). z streamed from LDS, unroll capped so
// reads aren't all hoisted. Ref-bitwise chains; strict MRG pruning.
// ---------------------------------------------------------------------------
__global__ __launch_bounds__(256, 2) void vq_select(const float* __restrict__ hid,
                                                    const float* __restrict__ emb,
                                                    const float* __restrict__ esq,
                                                    const float* __restrict__ Mm,
                                                    float* __restrict__ out_idx) {
#pragma clang fp contract(off)
    __shared__ float z_s[64][68];
    __shared__ float zsq_s[64];
    __shared__ float bD[64];
    __shared__ int   bI[64];
    __shared__ float d4s[4][64];
    __shared__ int   i4s[4][64];
    __shared__ int   list[64];
    __shared__ int   cnt;

    const int tid = threadIdx.x;
    const int lane = tid & 63;
    const int w = tid >> 6;
    const int t0 = blockIdx.x * 64;

    // ---- stage z into LDS ----
    {
        const int t = tid >> 2;
        const int j4 = (tid & 3) * 4;          // float4 index
        const float4* src = (const float4*)(hid + (size_t)(t0 + t) * DIM);
        float4* dst = (float4*)(&z_s[t][0]);
#pragma unroll
        for (int i = 0; i < 4; ++i) dst[j4 + i] = src[j4 + i];
    }
    __syncthreads();

    // ---- per-token: zsq (numpy pairwise), best init from Mm row max ----
    if (tid < 64) {
        const float* zr = &z_s[tid][0];
        float r[8];
#pragma unroll
        for (int q = 0; q < 8; ++q) {
            float x = zr[q]; r[q] = x * x;
#pragma unroll
            for (int m = 1; m < 8; ++m) {
                float y = zr[q + 8 * m];
                float sq = y * y;
                r[q] = r[q] + sq;
            }
        }
        const float zsq = ((r[0] + r[1]) + (r[2] + r[3])) + ((r[4] + r[5]) + (r[6] + r[7]));
        const float* mr = Mm + (size_t)(t0 + tid) * NCHK;
        float mx = mr[0];
#pragma unroll
        for (int c = 1; c < NCHK; ++c) mx = fmaxf(mx, mr[c]);
        const float eps = sqrtf(zsq) * 2.5e-6f + 2e-7f;
        zsq_s[tid] = zsq;
        bD[tid] = zsq - 2.0f * mx + 2.0f * eps + DINIT;   // >= true best fl-d
        bI[tid] = 0;
    }

    for (int c = 0; c < NCHK; ++c) {
        d4s[w][lane] = 3.0e38f;
        i4s[w][lane] = 0;
        if (tid == 0) cnt = 0;
        __syncthreads();
        if (tid < 64) {
            const float zsq = zsq_s[tid];
            const float eps = sqrtf(zsq) * 2.5e-6f + 2e-7f;
            const float m = Mm[(size_t)(t0 + tid) * NCHK + c];
            const float bound = fmaf(-2.0f, m + eps, zsq) - MRG;
            if (bound < bD[tid]) { const int p = atomicAdd(&cnt, 1); list[p] = tid; }
        }
        __syncthreads();
        const int nl = cnt;
        if (nl == 0) continue;

        {   // wave w evaluates its 64-code slice against all survivors
            const int k = c * 256 + 64 * w + lane;
            float ev[64];
            {
                const float4* pE = (const float4*)(emb + (size_t)k * DIM);
#pragma unroll
                for (int i = 0; i < 16; ++i) {
                    const float4 v = pE[i];
                    ev[4 * i] = v.x; ev[4 * i + 1] = v.y;
                    ev[4 * i + 2] = v.z; ev[4 * i + 3] = v.w;
                }
            }
            // PIN: force each ev element into a resident VGPR; the opaque asm
            // blocks rematerialized global re-loads inside the p-loop (R11 bug).
#pragma unroll
            for (int i = 0; i < 64; ++i) asm volatile("" : "+v"(ev[i]));
            const float ek = esq[k];

            for (int p = 0; p < nl; p += 2) {
                const int tP = list[p];
                const int hasQ = (p + 1 < nl);
                const int tQ = hasQ ? list[p + 1] : tP;
                const float4* zP = (const float4*)(&z_s[tP][0]);
                const float4* zQ = (const float4*)(&z_s[tQ][0]);
                float accP, accQ;
                {
                    const float4 a = zP[0], b = zQ[0];
                    accP = a.x * ev[0];            accQ = b.x * ev[0];
                    accP = fmaf(a.y, ev[1], accP); accQ = fmaf(b.y, ev[1], accQ);
                    accP = fmaf(a.z, ev[2], accP); accQ = fmaf(b.z, ev[2], accQ);
                    accP = fmaf(a.w, ev[3], accP); accQ = fmaf(b.w, ev[3], accQ);
                }
#pragma unroll 4
                for (int i = 1; i < 16; ++i) {
                    const float4 a = zP[i], b = zQ[i];
                    accP = fmaf(a.x, ev[4 * i + 0], accP); accQ = fmaf(b.x, ev[4 * i + 0], accQ);
                    accP = fmaf(a.y, ev[4 * i + 1], accP); accQ = fmaf(b.y, ev[4 * i + 1], accQ);
                    accP = fmaf(a.z, ev[4 * i + 2], accP); accQ = fmaf(b.z, ev[4 * i + 2], accQ);
                    accP = fmaf(a.w, ev[4 * i + 3], accP); accQ = fmaf(b.w, ev[4 * i + 3], accQ);
                }
                float dP = fmaf(-2.0f, accP, zsq_s[tP] + ek);
                int iP = k;
#pragma unroll
                for (int m = 1; m < 64; m <<= 1) {
                    const float ov = __shfl_xor(dP, m, 64);
                    const int   oi = __shfl_xor(iP, m, 64);
                    if (ov < dP || (ov == dP && oi < iP)) { dP = ov; iP = oi; }
                }
                if (lane == 0) { d4s[w][tP] = dP; i4s[w][tP] = iP; }
                if (hasQ) {
                    float dQ = fmaf(-2.0f, accQ, zsq_s[tQ] + ek);
                    int iQ = k;
#pragma unroll
                    for (int m = 1; m < 64; m <<= 1) {
                        const float ov = __shfl_xor(dQ, m, 64);
                        const int   oi = __shfl_xor(iQ, m, 64);
                        if (ov < dQ || (ov == dQ && oi < iQ)) { dQ = ov; iQ = oi; }
                    }
                    if (lane == 0) { d4s[w][tQ] = dQ; i4s[w][tQ] = iQ; }
                }
            }
        }
        __syncthreads();
        if (tid < 64) {
#pragma unroll
            for (int s = 0; s < 4; ++s) {      // ascending slices = ascending k
                const float dv = d4s[s][tid];
                const int iv = i4s[s][tid];
                if (dv < bD[tid] || (dv == bD[tid] && iv < bI[tid])) {
                    bD[tid] = dv; bI[tid] = iv;
                }
            }
        }
        __syncthreads();
    }

    if (tid < 64) out_idx[t0 + tid] = (float)bI[tid];
}

// ---------------------------------------------------------------------------
// Outputs: z_q = h + (q - h), loss partials (proven form).
// ---------------------------------------------------------------------------
__global__ __launch_bounds__(256) void vq_finish(const float* __restrict__ hid,
                                                 const float* __restrict__ emb,
                                                 const float* __restrict__ out_idx,
                                                 float* __restrict__ out_zq,
                                                 float* __restrict__ partials) {
#pragma clang fp contract(off)
    __shared__ float lred[4];
    const int tid = threadIdx.x;
    const int t = blockIdx.x * 256 + tid;

    const int bi = (int)out_idx[t];

    const float4* q4 = (const float4*)(emb + (size_t)bi * DIM);
    const float4* h4 = (const float4*)(hid + (size_t)t * DIM);
    float4* o4 = (float4*)(out_zq + (size_t)t * DIM);
    float lsum = 0.f;
#pragma unroll
    for (int i = 0; i < 16; ++i) {
        const float4 q = q4[i];
        const float4 h = h4[i];
        float4 zq;
        float dx;
        dx = q.x - h.x; zq.x = h.x + dx; lsum += dx * dx;
        dx = q.y - h.y; zq.y = h.y + dx; lsum += dx * dx;
        dx = q.z - h.z; zq.z = h.z + dx; lsum += dx * dx;
        dx = q.w - h.w; zq.w = h.w + dx; lsum += dx * dx;
        o4[i] = zq;
    }

#pragma unroll
    for (int off = 32; off >= 1; off >>= 1) lsum += __shfl_xor(lsum, off, 64);
    const int wid = tid >> 6;
    if ((tid & 63) == 0) lred[wid] = lsum;
    __syncthreads();
    if (tid == 0) partials[blockIdx.x] = (lred[0] + lred[1]) + (lred[2] + lred[3]);
}

__global__ __launch_bounds__(128) void loss_kernel(const float* __restrict__ partials,
                                                   float* __restrict__ out_loss) {
#pragma clang fp contract(off)
    __shared__ float s[128];
    const int t = threadIdx.x;
    s[t] = partials[t];
    __syncthreads();
    for (int off = 64; off >= 1; off >>= 1) {
        if (t < off) s[t] = s[t] + s[t + off];
        __syncthreads();
    }
    if (t == 0) {
        const float m = s[0] * (1.0f / 2097152.0f);  // exact: /2^21
        out_loss[0] = m + 0.25f * m;
    }
}

extern "C" void kernel_launch(void* const* d_in, const int* in_sizes, int n_in,
                              void* d_out, int out_size, void* d_ws, size_t ws_size,
                              hipStream_t stream) {
    const float* hid = (const float*)d_in[0];
    const float* emb = (const float*)d_in[1];
    float* out = (float*)d_out;
    float* ws  = (float*)d_ws;
    float*  esq   = ws + WS_ESQ;
    ushort* ehi   = (ushort*)(ws + WS_EHI);
    float*  parts = ws + WS_PART;
    float*  Mm    = out;            // zq region scratch; finish overwrites later

    esq_kernel<<<K_CODES / 32, 256, 0, stream>>>(emb, esq);
    pack_hi<<<K_CODES / 256, 256, 0, stream>>>(emb, ehi);
    vq_mfma<<<N_TOK / 64, 256, 0, stream>>>(hid, ehi, Mm);
    vq_select<<<N_TOK / 64, 256, 0, stream>>>(hid, emb, esq, Mm, out + IDX_OFF);
    vq_finish<<<N_TOK / 256, 256, 0, stream>>>(hid, emb, out + IDX_OFF, out, parts);
    loss_kernel<<<1, 128, 0, stream>>>(parts, out + LOSS_OFF);
}

// Round 13
// 472.354 us; speedup vs baseline: 1.2193x; 1.2193x over previous
//
#include <hip/hip_runtime.h>
#include <cfloat>

#define N_TOK   32768
#define DIM     64
#define K_CODES 8192
#define NCHK    64                 // 128-code chunks

#define IDX_OFF  (N_TOK * DIM)
#define LOSS_OFF (N_TOK * DIM + N_TOK)

// ws layout (float units): esq 8192 + ehiT 262144 (1MB packed bf16) + parts
#define WS_ESQ   0
#define WS_EHIT  8192
#define WS_PART  270336
// out zq-region scratch (dead until vq_finish):
//   eT (f32 transposed emb) at out+0 : 524288 floats
//   Mm (bf16-up, [chunk][token]) at out+524288 : 2097152 ushorts

#define MRG   2e-5f     // strict slack: bound < every computed fl-d in chunk
#define DINIT 6e-5f     // init slack (covers esq_max + fl-roundings + Mm bf16-up ulp)

typedef __attribute__((ext_vector_type(8)))  short bf16x8;
typedef __attribute__((ext_vector_type(16))) float f32x16;

__device__ inline ushort f2bf(float x) {          // round-to-nearest-even
    unsigned u = __float_as_uint(x);
    return (ushort)((u + 0x7FFFu + ((u >> 16) & 1u)) >> 16);
}
__device__ inline float bf2f(ushort h) { return __uint_as_float(((unsigned)h) << 16); }
__device__ inline ushort f2bf_up(float x) {       // round toward +inf (conservative)
    unsigned u = __float_as_uint(x);
    return (x >= 0.0f) ? (ushort)((u + 0xFFFFu) >> 16) : (ushort)(u >> 16);
}

// ---------------------------------------------------------------------------
// e_sq[k] = numpy-pairwise sum of squares (bitwise np order) — proven R1-R12.
// ---------------------------------------------------------------------------
__global__ __launch_bounds__(256) void esq_kernel(const float* __restrict__ emb,
                                                  float* __restrict__ esq) {
#pragma clang fp contract(off)
    const int tid = threadIdx.x;
    const int q = tid & 7;
    const int code = blockIdx.x * 32 + (tid >> 3);
    const float* row = emb + code * DIM;
    float x = row[q];
    float r = x * x;
#pragma unroll
    for (int m = 1; m < 8; ++m) {
        float y = row[q + 8 * m];
        float sq = y * y;
        r = r + sq;
    }
    r = r + __shfl_xor(r, 1, 64);
    r = r + __shfl_xor(r, 2, 64);
    r = r + __shfl_xor(r, 4, 64);
    if (q == 0) esq[code] = r;
}

// ---------------------------------------------------------------------------
// Pack: ehiT = bf16 e in MFMA-A-fragment order (coalesced b128 A-loads):
//   ehiT[(((sc*4+q)*2+h)*128 + lc)*8 + e] = bf16(emb[sc*128+lc][16q+8h+e])
// eT = exact f32 transpose: eT[j*8192 + k] = emb[k][j]  (coalesced streaming)
// ---------------------------------------------------------------------------
__global__ __launch_bounds__(256) void pack2(const float* __restrict__ emb,
                                             ushort* __restrict__ ehiT,
                                             float* __restrict__ eT) {
#pragma clang fp contract(off)
    const int k = blockIdx.x * 256 + threadIdx.x;   // 8192 codes
    float v[64];
    {
        const float4* ep = (const float4*)(emb + (size_t)k * DIM);
#pragma unroll
        for (int i = 0; i < 16; ++i) {
            const float4 a = ep[i];
            v[4 * i] = a.x; v[4 * i + 1] = a.y; v[4 * i + 2] = a.z; v[4 * i + 3] = a.w;
        }
    }
#pragma unroll
    for (int j = 0; j < 64; ++j) eT[(size_t)j * K_CODES + k] = v[j];
    const int sc = k >> 7, lc = k & 127;
#pragma unroll
    for (int q = 0; q < 4; ++q)
#pragma unroll
        for (int h = 0; h < 2; ++h) {
            bf16x8 o;
#pragma unroll
            for (int e = 0; e < 8; ++e) o[e] = (short)f2bf(v[16 * q + 8 * h + e]);
            *(bf16x8*)(ehiT + ((((size_t)sc * 4 + q) * 2 + h) * 128 + lc) * 8) = o;
        }
}

// ---------------------------------------------------------------------------
// MFMA sweep v3: block = 64 tokens; wave w sweeps chunks sc = 4g+w alone
// (full 128 codes via 4 row-groups) -> per-token chunk max needs only
// shfl_xor(32); NO LDS, NO barriers. A-loads coalesced from ehiT.
// B=z col=token mapping proven in R10/R11. Mm bf16-up (conservative).
// ---------------------------------------------------------------------------
__global__ __launch_bounds__(256, 2) void vq_mfma(const float* __restrict__ hid,
                                                  const ushort* __restrict__ ehiT,
                                                  ushort* __restrict__ Mm) {
#pragma clang fp contract(off)
    const int tid = threadIdx.x;
    const int lane = tid & 63;
    const int w = tid >> 6;
    const int h = lane >> 5;
    const int t0 = blockIdx.x * 64;

    // ---- B fragments: z hi/lo, 2 token-sets x 4 K-steps (proven build) ----
    bf16x8 z_hi[2][4], z_lo[2][4];
#pragma unroll
    for (int ts = 0; ts < 2; ++ts)
#pragma unroll
    for (int q = 0; q < 4; ++q) {
        const float* zp = hid + (size_t)(t0 + 32 * ts + (lane & 31)) * DIM + 16 * q + 8 * h;
        const float4 u0 = *(const float4*)zp;
        const float4 u1 = *(const float4*)(zp + 4);
        const float zz[8] = {u0.x, u0.y, u0.z, u0.w, u1.x, u1.y, u1.z, u1.w};
        bf16x8 hv, lv;
#pragma unroll
        for (int i = 0; i < 8; ++i) {
            const ushort hb = f2bf(zz[i]);
            hv[i] = (short)hb;
            lv[i] = (short)f2bf(zz[i] - bf2f(hb));
        }
        z_hi[ts][q] = hv; z_lo[ts][q] = lv;
    }

    f32x16 zc;
#pragma unroll
    for (int i = 0; i < 16; ++i) zc[i] = 0.0f;

    for (int g = 0; g < 16; ++g) {
        const int sc = 4 * g + w;
        float wm0 = -3.0e38f, wm1 = -3.0e38f;
#pragma unroll
        for (int r = 0; r < 4; ++r) {
            bf16x8 A[4];
#pragma unroll
            for (int q = 0; q < 4; ++q)
                A[q] = *(const bf16x8*)(ehiT +
                        ((((size_t)sc * 4 + q) * 2 + h) * 128 + 32 * r + (lane & 31)) * 8);
            f32x16 d0, d1;
#pragma unroll
            for (int q = 0; q < 4; ++q) {
                if (q == 0) {
                    d0 = __builtin_amdgcn_mfma_f32_32x32x16_bf16(A[0], z_hi[0][0], zc, 0, 0, 0);
                    d1 = __builtin_amdgcn_mfma_f32_32x32x16_bf16(A[0], z_hi[1][0], zc, 0, 0, 0);
                } else {
                    d0 = __builtin_amdgcn_mfma_f32_32x32x16_bf16(A[q], z_hi[0][q], d0, 0, 0, 0);
                    d1 = __builtin_amdgcn_mfma_f32_32x32x16_bf16(A[q], z_hi[1][q], d1, 0, 0, 0);
                }
                d0 = __builtin_amdgcn_mfma_f32_32x32x16_bf16(A[q], z_lo[0][q], d0, 0, 0, 0);
                d1 = __builtin_amdgcn_mfma_f32_32x32x16_bf16(A[q], z_lo[1][q], d1, 0, 0, 0);
            }
#pragma unroll
            for (int i = 0; i < 16; ++i) {
                wm0 = fmaxf(wm0, d0[i]);
                wm1 = fmaxf(wm1, d1[i]);
            }
        }
        wm0 = fmaxf(wm0, __shfl_xor(wm0, 32, 64));
        wm1 = fmaxf(wm1, __shfl_xor(wm1, 32, 64));
        if (lane < 32) {
            Mm[(size_t)sc * N_TOK + t0 + lane]      = f2bf_up(wm0);
            Mm[(size_t)sc * N_TOK + t0 + 32 + lane] = f2bf_up(wm1);
        }
    }
}

// ---------------------------------------------------------------------------
// Exact selection v4: block = 64 tokens. Wave w handles chunks 4g+w; per
// chunk, ballot builds a survivor mask; groups of <=4 survivors evaluated
// with COALESCED eT streaming (float2/j shared by 4 chains) + uniform-LDS z.
// Merge per 4-chunk group in ascending order. Ref-bitwise chains throughout.
// ---------------------------------------------------------------------------
__global__ __launch_bounds__(256, 2) void vq_select(const float* __restrict__ hid,
                                                    const float* __restrict__ eT,
                                                    const float* __restrict__ esq,
                                                    const ushort* __restrict__ Mm,
                                                    float* __restrict__ out_idx) {
#pragma clang fp contract(off)
    __shared__ float z_s[64][68];
    __shared__ float zsq_s[64];
    __shared__ float bD[64];
    __shared__ int   bI[64];
    __shared__ float d4s[4][64];
    __shared__ int   i4s[4][64];

    const int tid = threadIdx.x;
    const int lane = tid & 63;
    const int w = tid >> 6;
    const int t0 = blockIdx.x * 64;

    // ---- stage z into LDS ----
    {
        const int t = tid >> 2;
        const int j4 = (tid & 3) * 4;
        const float4* src = (const float4*)(hid + (size_t)(t0 + t) * DIM);
        float4* dst = (float4*)(&z_s[t][0]);
#pragma unroll
        for (int i = 0; i < 4; ++i) dst[j4 + i] = src[j4 + i];
    }
    __syncthreads();

    // ---- per-token: zsq (numpy pairwise), best init from Mm row max ----
    if (tid < 64) {
        const float* zr = &z_s[tid][0];
        float r[8];
#pragma unroll
        for (int q = 0; q < 8; ++q) {
            float x = zr[q]; r[q] = x * x;
#pragma unroll
            for (int m = 1; m < 8; ++m) {
                float y = zr[q + 8 * m];
                float sq = y * y;
                r[q] = r[q] + sq;
            }
        }
        const float zsq = ((r[0] + r[1]) + (r[2] + r[3])) + ((r[4] + r[5]) + (r[6] + r[7]));
        float mx = bf2f(Mm[(size_t)0 * N_TOK + t0 + tid]);
#pragma unroll 8
        for (int c = 1; c < NCHK; ++c) mx = fmaxf(mx, bf2f(Mm[(size_t)c * N_TOK + t0 + tid]));
        const float eps = sqrtf(zsq) * 2.5e-6f + 2e-7f;
        zsq_s[tid] = zsq;
        bD[tid] = zsq - 2.0f * mx + 2.0f * eps + DINIT;   // >= true best fl-d
        bI[tid] = 0;
#pragma unroll
        for (int ww = 0; ww < 4; ++ww) { d4s[ww][tid] = 3.0e38f; i4s[ww][tid] = 0; }
    }
    __syncthreads();

    for (int g = 0; g < 16; ++g) {
        const int c = 4 * g + w;
        // bound check: lane = token
        const float zsqL = zsq_s[lane];
        const float epsL = sqrtf(zsqL) * 2.5e-6f + 2e-7f;
        const float m = bf2f(Mm[(size_t)c * N_TOK + t0 + lane]);
        const float bound = fmaf(-2.0f, m + epsL, zsqL) - MRG;
        unsigned long long mask = __ballot(bound < bD[lane]);

        const int k0 = c * 128 + 2 * lane;
        while (mask) {
            int G = 1;
            const int tA = __ffsll(mask) - 1; mask &= mask - 1;
            int tB = tA, tC = tA, tD = tA;
            if (mask) { tB = __ffsll(mask) - 1; mask &= mask - 1; G = 2; }
            if (mask) { tC = __ffsll(mask) - 1; mask &= mask - 1; G = 3; }
            if (mask) { tD = __ffsll(mask) - 1; mask &= mask - 1; G = 4; }

            const float* eb = eT + k0;
            float aA0, aA1, aB0, aB1, aC0, aC1, aD0, aD1;
#define SUBSTEP(J, COMP) { \
    const float2 e2 = *(const float2*)(eb + (size_t)(J) * K_CODES); \
    aA0 = fmaf(zA4.COMP, e2.x, aA0); aA1 = fmaf(zA4.COMP, e2.y, aA1); \
    aB0 = fmaf(zB4.COMP, e2.x, aB0); aB1 = fmaf(zB4.COMP, e2.y, aB1); \
    aC0 = fmaf(zC4.COMP, e2.x, aC0); aC1 = fmaf(zC4.COMP, e2.y, aC1); \
    aD0 = fmaf(zD4.COMP, e2.x, aD0); aD1 = fmaf(zD4.COMP, e2.y, aD1); }
            {   // i = 0: j=0 peeled as mul (bitwise head of chain)
                const float4 zA4 = *(const float4*)(&z_s[tA][0]);
                const float4 zB4 = *(const float4*)(&z_s[tB][0]);
                const float4 zC4 = *(const float4*)(&z_s[tC][0]);
                const float4 zD4 = *(const float4*)(&z_s[tD][0]);
                const float2 e0 = *(const float2*)(eb);
                aA0 = zA4.x * e0.x; aA1 = zA4.x * e0.y;
                aB0 = zB4.x * e0.x; aB1 = zB4.x * e0.y;
                aC0 = zC4.x * e0.x; aC1 = zC4.x * e0.y;
                aD0 = zD4.x * e0.x; aD1 = zD4.x * e0.y;
                SUBSTEP(1, y) SUBSTEP(2, z) SUBSTEP(3, w)
            }
#pragma unroll
            for (int i = 1; i < 16; ++i) {
                const float4 zA4 = *(const float4*)(&z_s[tA][4 * i]);
                const float4 zB4 = *(const float4*)(&z_s[tB][4 * i]);
                const float4 zC4 = *(const float4*)(&z_s[tC][4 * i]);
                const float4 zD4 = *(const float4*)(&z_s[tD][4 * i]);
                SUBSTEP(4 * i + 0, x) SUBSTEP(4 * i + 1, y)
                SUBSTEP(4 * i + 2, z) SUBSTEP(4 * i + 3, w)
            }
#undef SUBSTEP
            const float2 es2 = *(const float2*)(esq + k0);
#define FINISH(aX0, aX1, zqX, tX) { \
    const float sX0 = zqX + es2.x; \
    const float sX1 = zqX + es2.y; \
    float d0 = fmaf(-2.0f, aX0, sX0); \
    const float d1 = fmaf(-2.0f, aX1, sX1); \
    float dl = d0; int il = k0; \
    if (d1 < dl) { dl = d1; il = k0 + 1; } \
    _Pragma("unroll") \
    for (int mm = 1; mm < 64; mm <<= 1) { \
        const float ov = __shfl_xor(dl, mm, 64); \
        const int   oi = __shfl_xor(il, mm, 64); \
        if (ov < dl || (ov == dl && oi < il)) { dl = ov; il = oi; } \
    } \
    if (lane == 0) { d4s[w][tX] = dl; i4s[w][tX] = il; } }
            { const float zqA = zsq_s[tA]; FINISH(aA0, aA1, zqA, tA) }
            if (G >= 2) { const float zqB = zsq_s[tB]; FINISH(aB0, aB1, zqB, tB) }
            if (G >= 3) { const float zqC = zsq_s[tC]; FINISH(aC0, aC1, zqC, tC) }
            if (G >= 4) { const float zqD = zsq_s[tD]; FINISH(aD0, aD1, zqD, tD) }
#undef FINISH
        }
        __syncthreads();
        if (tid < 64) {
            float bd = bD[tid]; int bi = bI[tid];
#pragma unroll
            for (int ww = 0; ww < 4; ++ww) {   // ascending ww = ascending chunk
                const float dv = d4s[ww][tid];
                const int iv = i4s[ww][tid];
                if (dv < bd || (dv == bd && iv < bi)) { bd = dv; bi = iv; }
                d4s[ww][tid] = 3.0e38f; i4s[ww][tid] = 0;
            }
            bD[tid] = bd; bI[tid] = bi;
        }
        __syncthreads();
    }

    if (tid < 64) out_idx[t0 + tid] = (float)bI[tid];
}

// ---------------------------------------------------------------------------
// Outputs: z_q = h + (q - h), loss partials (proven form).
// ---------------------------------------------------------------------------
__global__ __launch_bounds__(256) void vq_finish(const float* __restrict__ hid,
                                                 const float* __restrict__ emb,
                                                 const float* __restrict__ out_idx,
                                                 float* __restrict__ out_zq,
                                                 float* __restrict__ partials) {
#pragma clang fp contract(off)
    __shared__ float lred[4];
    const int tid = threadIdx.x;
    const int t = blockIdx.x * 256 + tid;

    const int bi = (int)out_idx[t];

    const float4* q4 = (const float4*)(emb + (size_t)bi * DIM);
    const float4* h4 = (const float4*)(hid + (size_t)t * DIM);
    float4* o4 = (float4*)(out_zq + (size_t)t * DIM);
    float lsum = 0.f;
#pragma unroll
    for (int i = 0; i < 16; ++i) {
        const float4 q = q4[i];
        const float4 h = h4[i];
        float4 zq;
        float dx;
        dx = q.x - h.x; zq.x = h.x + dx; lsum += dx * dx;
        dx = q.y - h.y; zq.y = h.y + dx; lsum += dx * dx;
        dx = q.z - h.z; zq.z = h.z + dx; lsum += dx * dx;
        dx = q.w - h.w; zq.w = h.w + dx; lsum += dx * dx;
        o4[i] = zq;
    }

#pragma unroll
    for (int off = 32; off >= 1; off >>= 1) lsum += __shfl_xor(lsum, off, 64);
    const int wid = tid >> 6;
    if ((tid & 63) == 0) lred[wid] = lsum;
    __syncthreads();
    if (tid == 0) partials[blockIdx.x] = (lred[0] + lred[1]) + (lred[2] + lred[3]);
}

__global__ __launch_bounds__(128) void loss_kernel(const float* __restrict__ partials,
                                                   float* __restrict__ out_loss) {
#pragma clang fp contract(off)
    __shared__ float s[128];
    const int t = threadIdx.x;
    s[t] = partials[t];
    __syncthreads();
    for (int off = 64; off >= 1; off >>= 1) {
        if (t < off) s[t] = s[t] + s[t + off];
        __syncthreads();
    }
    if (t == 0) {
        const float m = s[0] * (1.0f / 2097152.0f);  // exact: /2^21
        out_loss[0] = m + 0.25f * m;
    }
}

extern "C" void kernel_launch(void* const* d_in, const int* in_sizes, int n_in,
                              void* d_out, int out_size, void* d_ws, size_t ws_size,
                              hipStream_t stream) {
    const float* hid = (const float*)d_in[0];
    const float* emb = (const float*)d_in[1];
    float* out = (float*)d_out;
    float* ws  = (float*)d_ws;
    float*  esq   = ws + WS_ESQ;
    ushort* ehiT  = (ushort*)(ws + WS_EHIT);
    float*  parts = ws + WS_PART;
    float*  eT    = out;                               // zq-region scratch
    ushort* Mm    = (ushort*)(out + 524288);           // zq-region scratch

    esq_kernel<<<K_CODES / 32, 256, 0, stream>>>(emb, esq);
    pack2<<<K_CODES / 256, 256, 0, stream>>>(emb, ehiT, eT);
    vq_mfma<<<N_TOK / 64, 256, 0, stream>>>(hid, ehiT, Mm);
    vq_select<<<N_TOK / 64, 256, 0, stream>>>(hid, eT, esq, Mm, out + IDX_OFF);
    vq_finish<<<N_TOK / 256, 256, 0, stream>>>(hid, emb, out + IDX_OFF, out, parts);
    loss_kernel<<<1, 128, 0, stream>>>(parts, out + LOSS_OFF);
}

// Round 14
// 282.046 us; speedup vs baseline: 2.0420x; 1.6747x over previous
//
#include <hip/hip_runtime.h>
#include <cfloat>

#define N_TOK   32768
#define DIM     64
#define K_CODES 8192
#define NCHK    64                 // 128-code chunks

#define IDX_OFF  (N_TOK * DIM)
#define LOSS_OFF (N_TOK * DIM + N_TOK)

// ws layout (float units): esq 8192 + ehiT 262144 (1MB packed bf16) + parts
#define WS_ESQ   0
#define WS_EHIT  8192
#define WS_PART  270336
// out zq-region scratch (dead until vq_finish):
//   eT (f32 transposed emb) at out+0 : 524288 floats
//   Mm (bf16-up, [chunk][token]) at out+524288 : 2097152 ushorts

#define MRG   2e-5f     // strict slack: bound < every computed fl-d in chunk
#define DINIT 6e-5f     // init slack (covers esq_max + fl-roundings + Mm bf16-up ulp)

typedef __attribute__((ext_vector_type(8)))  short bf16x8;
typedef __attribute__((ext_vector_type(16))) float f32x16;

__device__ inline ushort f2bf(float x) {          // round-to-nearest-even
    unsigned u = __float_as_uint(x);
    return (ushort)((u + 0x7FFFu + ((u >> 16) & 1u)) >> 16);
}
__device__ inline float bf2f(ushort h) { return __uint_as_float(((unsigned)h) << 16); }
__device__ inline ushort f2bf_up(float x) {       // round toward +inf (conservative)
    unsigned u = __float_as_uint(x);
    return (x >= 0.0f) ? (ushort)((u + 0xFFFFu) >> 16) : (ushort)(u >> 16);
}

// ---------------------------------------------------------------------------
// e_sq[k] = numpy-pairwise sum of squares (bitwise np order) — proven R1-R13.
// ---------------------------------------------------------------------------
__global__ __launch_bounds__(256) void esq_kernel(const float* __restrict__ emb,
                                                  float* __restrict__ esq) {
#pragma clang fp contract(off)
    const int tid = threadIdx.x;
    const int q = tid & 7;
    const int code = blockIdx.x * 32 + (tid >> 3);
    const float* row = emb + code * DIM;
    float x = row[q];
    float r = x * x;
#pragma unroll
    for (int m = 1; m < 8; ++m) {
        float y = row[q + 8 * m];
        float sq = y * y;
        r = r + sq;
    }
    r = r + __shfl_xor(r, 1, 64);
    r = r + __shfl_xor(r, 2, 64);
    r = r + __shfl_xor(r, 4, 64);
    if (q == 0) esq[code] = r;
}

// ---------------------------------------------------------------------------
// Pack: ehiT = bf16 e in MFMA-A-fragment order (coalesced b128 A-loads);
// eT = exact f32 transpose eT[j*8192+k] = emb[k][j] (coalesced streaming).
// ---------------------------------------------------------------------------
__global__ __launch_bounds__(256) void pack2(const float* __restrict__ emb,
                                             ushort* __restrict__ ehiT,
                                             float* __restrict__ eT) {
#pragma clang fp contract(off)
    const int k = blockIdx.x * 256 + threadIdx.x;   // 8192 codes
    float v[64];
    {
        const float4* ep = (const float4*)(emb + (size_t)k * DIM);
#pragma unroll
        for (int i = 0; i < 16; ++i) {
            const float4 a = ep[i];
            v[4 * i] = a.x; v[4 * i + 1] = a.y; v[4 * i + 2] = a.z; v[4 * i + 3] = a.w;
        }
    }
#pragma unroll
    for (int j = 0; j < 64; ++j) eT[(size_t)j * K_CODES + k] = v[j];
    const int sc = k >> 7, lc = k & 127;
#pragma unroll
    for (int q = 0; q < 4; ++q)
#pragma unroll
        for (int h = 0; h < 2; ++h) {
            bf16x8 o;
#pragma unroll
            for (int e = 0; e < 8; ++e) o[e] = (short)f2bf(v[16 * q + 8 * h + e]);
            *(bf16x8*)(ehiT + ((((size_t)sc * 4 + q) * 2 + h) * 128 + lc) * 8) = o;
        }
}

// ---------------------------------------------------------------------------
// MFMA sweep v3 (unchanged from R13, passed): wave w sweeps chunks 4g+w;
// per-token chunk max via shfl_xor(32); no LDS/barriers; coalesced A-loads.
// ---------------------------------------------------------------------------
__global__ __launch_bounds__(256, 2) void vq_mfma(const float* __restrict__ hid,
                                                  const ushort* __restrict__ ehiT,
                                                  ushort* __restrict__ Mm) {
#pragma clang fp contract(off)
    const int tid = threadIdx.x;
    const int lane = tid & 63;
    const int w = tid >> 6;
    const int h = lane >> 5;
    const int t0 = blockIdx.x * 64;

    bf16x8 z_hi[2][4], z_lo[2][4];
#pragma unroll
    for (int ts = 0; ts < 2; ++ts)
#pragma unroll
    for (int q = 0; q < 4; ++q) {
        const float* zp = hid + (size_t)(t0 + 32 * ts + (lane & 31)) * DIM + 16 * q + 8 * h;
        const float4 u0 = *(const float4*)zp;
        const float4 u1 = *(const float4*)(zp + 4);
        const float zz[8] = {u0.x, u0.y, u0.z, u0.w, u1.x, u1.y, u1.z, u1.w};
        bf16x8 hv, lv;
#pragma unroll
        for (int i = 0; i < 8; ++i) {
            const ushort hb = f2bf(zz[i]);
            hv[i] = (short)hb;
            lv[i] = (short)f2bf(zz[i] - bf2f(hb));
        }
        z_hi[ts][q] = hv; z_lo[ts][q] = lv;
    }

    f32x16 zc;
#pragma unroll
    for (int i = 0; i < 16; ++i) zc[i] = 0.0f;

    for (int g = 0; g < 16; ++g) {
        const int sc = 4 * g + w;
        float wm0 = -3.0e38f, wm1 = -3.0e38f;
#pragma unroll
        for (int r = 0; r < 4; ++r) {
            bf16x8 A[4];
#pragma unroll
            for (int q = 0; q < 4; ++q)
                A[q] = *(const bf16x8*)(ehiT +
                        ((((size_t)sc * 4 + q) * 2 + h) * 128 + 32 * r + (lane & 31)) * 8);
            f32x16 d0, d1;
#pragma unroll
            for (int q = 0; q < 4; ++q) {
                if (q == 0) {
                    d0 = __builtin_amdgcn_mfma_f32_32x32x16_bf16(A[0], z_hi[0][0], zc, 0, 0, 0);
                    d1 = __builtin_amdgcn_mfma_f32_32x32x16_bf16(A[0], z_hi[1][0], zc, 0, 0, 0);
                } else {
                    d0 = __builtin_amdgcn_mfma_f32_32x32x16_bf16(A[q], z_hi[0][q], d0, 0, 0, 0);
                    d1 = __builtin_amdgcn_mfma_f32_32x32x16_bf16(A[q], z_hi[1][q], d1, 0, 0, 0);
                }
                d0 = __builtin_amdgcn_mfma_f32_32x32x16_bf16(A[q], z_lo[0][q], d0, 0, 0, 0);
                d1 = __builtin_amdgcn_mfma_f32_32x32x16_bf16(A[q], z_lo[1][q], d1, 0, 0, 0);
            }
#pragma unroll
            for (int i = 0; i < 16; ++i) {
                wm0 = fmaxf(wm0, d0[i]);
                wm1 = fmaxf(wm1, d1[i]);
            }
        }
        wm0 = fmaxf(wm0, __shfl_xor(wm0, 32, 64));
        wm1 = fmaxf(wm1, __shfl_xor(wm1, 32, 64));
        if (lane < 32) {
            Mm[(size_t)sc * N_TOK + t0 + lane]      = f2bf_up(wm0);
            Mm[(size_t)sc * N_TOK + t0 + 32 + lane] = f2bf_up(wm1);
        }
    }
}

// ---------------------------------------------------------------------------
// Exact selection v5: chunks strictly sequential (bD merged every chunk =
// tightest pruning, R10/R11 semantics). Per surviving chunk, waves take
// survivor tokens round-robin, ONE token per wave at a time: lane owns 2
// codes, e streamed coalesced from eT (float2/j), z uniform-LDS broadcast.
// Live set ~12 VGPR -> nothing to spill/remat. Ref-bitwise chains.
// ---------------------------------------------------------------------------
__global__ __launch_bounds__(256, 2) void vq_select(const float* __restrict__ hid,
                                                    const float* __restrict__ eT,
                                                    const float* __restrict__ esq,
                                                    const ushort* __restrict__ Mm,
                                                    float* __restrict__ out_idx) {
#pragma clang fp contract(off)
    __shared__ float z_s[64][68];
    __shared__ float zsq_s[64];
    __shared__ float bD[64];
    __shared__ int   bI[64];
    __shared__ float d1s[64];
    __shared__ int   i1s[64];
    __shared__ int   list[64];
    __shared__ int   cnt;

    const int tid = threadIdx.x;
    const int lane = tid & 63;
    const int w = tid >> 6;
    const int t0 = blockIdx.x * 64;

    // ---- stage z into LDS ----
    {
        const int t = tid >> 2;
        const int j4 = (tid & 3) * 4;
        const float4* src = (const float4*)(hid + (size_t)(t0 + t) * DIM);
        float4* dst = (float4*)(&z_s[t][0]);
#pragma unroll
        for (int i = 0; i < 4; ++i) dst[j4 + i] = src[j4 + i];
    }
    __syncthreads();

    // ---- per-token: zsq (numpy pairwise), best init from Mm column max ----
    if (tid < 64) {
        const float* zr = &z_s[tid][0];
        float r[8];
#pragma unroll
        for (int q = 0; q < 8; ++q) {
            float x = zr[q]; r[q] = x * x;
#pragma unroll
            for (int m = 1; m < 8; ++m) {
                float y = zr[q + 8 * m];
                float sq = y * y;
                r[q] = r[q] + sq;
            }
        }
        const float zsq = ((r[0] + r[1]) + (r[2] + r[3])) + ((r[4] + r[5]) + (r[6] + r[7]));
        float mx = bf2f(Mm[(size_t)0 * N_TOK + t0 + tid]);
#pragma unroll 8
        for (int c = 1; c < NCHK; ++c) mx = fmaxf(mx, bf2f(Mm[(size_t)c * N_TOK + t0 + tid]));
        const float eps = sqrtf(zsq) * 2.5e-6f + 2e-7f;
        zsq_s[tid] = zsq;
        bD[tid] = zsq - 2.0f * mx + 2.0f * eps + DINIT;   // >= true best fl-d
        bI[tid] = 0;
    }

    for (int c = 0; c < NCHK; ++c) {
        if (tid < 64) { d1s[tid] = 3.0e38f; i1s[tid] = 0; }
        if (tid == 0) cnt = 0;
        __syncthreads();
        if (tid < 64) {
            const float zsq = zsq_s[tid];
            const float eps = sqrtf(zsq) * 2.5e-6f + 2e-7f;
            const float m = bf2f(Mm[(size_t)c * N_TOK + t0 + tid]);
            const float bound = fmaf(-2.0f, m + eps, zsq) - MRG;
            if (bound < bD[tid]) { const int p = atomicAdd(&cnt, 1); list[p] = tid; }
        }
        __syncthreads();
        const int nl = cnt;
        if (nl) {
            const int k0 = c * 128 + 2 * lane;
            const float* eb = eT + k0;
            const float2 es2 = *(const float2*)(esq + k0);

            for (int i = w; i < nl; i += 4) {
                const int tt = list[i];                 // wave-uniform
                const float zsqT = zsq_s[tt];
                const float4* zp = (const float4*)(&z_s[tt][0]);
                float a0, a1;
                {   // j = 0..3 (j=0 peeled as mul: bitwise head of chain)
                    const float4 zv = zp[0];
                    float2 e2 = *(const float2*)(eb);
                    a0 = zv.x * e2.x; a1 = zv.x * e2.y;
                    e2 = *(const float2*)(eb + (size_t)1 * K_CODES);
                    a0 = fmaf(zv.y, e2.x, a0); a1 = fmaf(zv.y, e2.y, a1);
                    e2 = *(const float2*)(eb + (size_t)2 * K_CODES);
                    a0 = fmaf(zv.z, e2.x, a0); a1 = fmaf(zv.z, e2.y, a1);
                    e2 = *(const float2*)(eb + (size_t)3 * K_CODES);
                    a0 = fmaf(zv.w, e2.x, a0); a1 = fmaf(zv.w, e2.y, a1);
                }
#pragma unroll
                for (int i2 = 1; i2 < 16; ++i2) {
                    const float4 zv = zp[i2];
                    float2 e2 = *(const float2*)(eb + (size_t)(4 * i2) * K_CODES);
                    a0 = fmaf(zv.x, e2.x, a0); a1 = fmaf(zv.x, e2.y, a1);
                    e2 = *(const float2*)(eb + (size_t)(4 * i2 + 1) * K_CODES);
                    a0 = fmaf(zv.y, e2.x, a0); a1 = fmaf(zv.y, e2.y, a1);
                    e2 = *(const float2*)(eb + (size_t)(4 * i2 + 2) * K_CODES);
                    a0 = fmaf(zv.z, e2.x, a0); a1 = fmaf(zv.z, e2.y, a1);
                    e2 = *(const float2*)(eb + (size_t)(4 * i2 + 3) * K_CODES);
                    a0 = fmaf(zv.w, e2.x, a0); a1 = fmaf(zv.w, e2.y, a1);
                }
                const float d0 = fmaf(-2.0f, a0, zsqT + es2.x);
                const float d1 = fmaf(-2.0f, a1, zsqT + es2.y);
                float dl = d0; int il = k0;
                if (d1 < dl) { dl = d1; il = k0 + 1; }   // tie keeps k0 (<k0+1)
#pragma unroll
                for (int m = 1; m < 64; m <<= 1) {
                    const float ov = __shfl_xor(dl, m, 64);
                    const int   oi = __shfl_xor(il, m, 64);
                    if (ov < dl || (ov == dl && oi < il)) { dl = ov; il = oi; }
                }
                if (lane == 0) { d1s[tt] = dl; i1s[tt] = il; }
            }
        }
        __syncthreads();
        if (tid < 64) {
            const float dv = d1s[tid];
            const int iv = i1s[tid];
            if (dv < bD[tid] || (dv == bD[tid] && iv < bI[tid])) {
                bD[tid] = dv; bI[tid] = iv;
            }
        }
        __syncthreads();
    }

    if (tid < 64) out_idx[t0 + tid] = (float)bI[tid];
}

// ---------------------------------------------------------------------------
// Outputs: z_q = h + (q - h), loss partials (proven form).
// ---------------------------------------------------------------------------
__global__ __launch_bounds__(256) void vq_finish(const float* __restrict__ hid,
                                                 const float* __restrict__ emb,
                                                 const float* __restrict__ out_idx,
                                                 float* __restrict__ out_zq,
                                                 float* __restrict__ partials) {
#pragma clang fp contract(off)
    __shared__ float lred[4];
    const int tid = threadIdx.x;
    const int t = blockIdx.x * 256 + tid;

    const int bi = (int)out_idx[t];

    const float4* q4 = (const float4*)(emb + (size_t)bi * DIM);
    const float4* h4 = (const float4*)(hid + (size_t)t * DIM);
    float4* o4 = (float4*)(out_zq + (size_t)t * DIM);
    float lsum = 0.f;
#pragma unroll
    for (int i = 0; i < 16; ++i) {
        const float4 q = q4[i];
        const float4 h = h4[i];
        float4 zq;
        float dx;
        dx = q.x - h.x; zq.x = h.x + dx; lsum += dx * dx;
        dx = q.y - h.y; zq.y = h.y + dx; lsum += dx * dx;
        dx = q.z - h.z; zq.z = h.z + dx; lsum += dx * dx;
        dx = q.w - h.w; zq.w = h.w + dx; lsum += dx * dx;
        o4[i] = zq;
    }

#pragma unroll
    for (int off = 32; off >= 1; off >>= 1) lsum += __shfl_xor(lsum, off, 64);
    const int wid = tid >> 6;
    if ((tid & 63) == 0) lred[wid] = lsum;
    __syncthreads();
    if (tid == 0) partials[blockIdx.x] = (lred[0] + lred[1]) + (lred[2] + lred[3]);
}

__global__ __launch_bounds__(128) void loss_kernel(const float* __restrict__ partials,
                                                   float* __restrict__ out_loss) {
#pragma clang fp contract(off)
    __shared__ float s[128];
    const int t = threadIdx.x;
    s[t] = partials[t];
    __syncthreads();
    for (int off = 64; off >= 1; off >>= 1) {
        if (t < off) s[t] = s[t] + s[t + off];
        __syncthreads();
    }
    if (t == 0) {
        const float m = s[0] * (1.0f / 2097152.0f);  // exact: /2^21
        out_loss[0] = m + 0.25f * m;
    }
}

extern "C" void kernel_launch(void* const* d_in, const int* in_sizes, int n_in,
                              void* d_out, int out_size, void* d_ws, size_t ws_size,
                              hipStream_t stream) {
    const float* hid = (const float*)d_in[0];
    const float* emb = (const float*)d_in[1];
    float* out = (float*)d_out;
    float* ws  = (float*)d_ws;
    float*  esq   = ws + WS_ESQ;
    ushort* ehiT  = (ushort*)(ws + WS_EHIT);
    float*  parts = ws + WS_PART;
    float*  eT    = out;                               // zq-region scratch
    ushort* Mm    = (ushort*)(out + 524288);           // zq-region scratch

    esq_kernel<<<K_CODES / 32, 256, 0, stream>>>(emb, esq);
    pack2<<<K_CODES / 256, 256, 0, stream>>>(emb, ehiT, eT);
    vq_mfma<<<N_TOK / 64, 256, 0, stream>>>(hid, ehiT, Mm);
    vq_select<<<N_TOK / 64, 256, 0, stream>>>(hid, eT, esq, Mm, out + IDX_OFF);
    vq_finish<<<N_TOK / 256, 256, 0, stream>>>(hid, emb, out + IDX_OFF, out, parts);
    loss_kernel<<<1, 128, 0, stream>>>(parts, out + LOSS_OFF);
}